// Round 11
// baseline (59.514 us; speedup 1.0000x reference)
//
#include <hip/hip_runtime.h>

#define BATCH 4096
#define SEQ   80
#define EMBED 100
#define UNITS 64
#define NTILE (BATCH / 16)      // 256 batch tiles of 16 rows
#define NVOC  10000
#define NVWV  ((NVOC + 15) / 16)   // 625 vocab tiles of 16 rows

typedef float f32x4  __attribute__((ext_vector_type(4)));
typedef short bf16x8 __attribute__((ext_vector_type(8)));

#define MFMA16 __builtin_amdgcn_mfma_f32_16x16x32_bf16

// ---- ws layout (bytes) ----
#define TAB_OFF 0u           // bf16 table[10000][64] = 1,280,000 B (L2-resident)
#define W1T_OFF 1280000u     // ushort[64*128] (k zero-padded to 128)
#define U1T_OFF 1296384u     // ushort[64*64]
#define W2T_OFF 1304576u
#define U2T_OFF 1312768u     // end = 1,320,960 B

__device__ __forceinline__ unsigned f2bfu(float f) {
    union { float f; unsigned u; } x; x.f = f;
    return (x.u + 0x7fffu + ((x.u >> 16) & 1u)) >> 16;   // RNE
}
__device__ __forceinline__ unsigned cvtpk(float lo, float hi) {
    unsigned r;
    asm("v_cvt_pk_bf16_f32 %0, %1, %2" : "=v"(r) : "v"(lo), "v"(hi));
    return r;
}
__device__ __forceinline__ float bflo(unsigned u) {
    union { unsigned u; float f; } x; x.u = u << 16; return x.f;
}
__device__ __forceinline__ float bfhi(unsigned u) {
    union { unsigned u; float f; } x; x.u = u & 0xffff0000u; return x.f;
}
// branch-free exact-tails tanh: 1 - 2/(e^{2x}+1)
__device__ __forceinline__ float fast_tanh(float x) {
    float e = __builtin_amdgcn_exp2f(x * 2.8853900817779268f);   // e^{2x}
    float r = __builtin_amdgcn_rcpf(e + 1.0f);
    return __builtin_fmaf(-2.0f, r, 1.0f);
}

// ---------------------------------------------------------------------------
// miniprep: transposed bf16 weight tables only (20480 elems total).
// ---------------------------------------------------------------------------
__global__ __launch_bounds__(256) void miniprep_kernel(
    const float* __restrict__ W1, const float* __restrict__ U1,
    const float* __restrict__ W2, const float* __restrict__ U2,
    char* __restrict__ ws)
{
    ushort* w1t = (ushort*)(ws + W1T_OFF);
    ushort* u1t = (ushort*)(ws + U1T_OFF);
    ushort* w2t = (ushort*)(ws + W2T_OFF);
    ushort* u2t = (ushort*)(ws + U2T_OFF);
    const int i = blockIdx.x * 256 + threadIdx.x;
    if (i < 8192) {                       // w1t[u][k], k padded to 128
        const int u = i >> 7, k = i & 127;
        w1t[i] = (k < EMBED) ? (ushort)f2bfu(W1[k * UNITS + u]) : (ushort)0;
    } else if (i < 12288) {
        const int j = i - 8192, u = j >> 6, k = j & 63;
        u1t[j] = (ushort)f2bfu(U1[k * UNITS + u]);
    } else if (i < 16384) {
        const int j = i - 12288, u = j >> 6, k = j & 63;
        w2t[j] = (ushort)f2bfu(W2[k * UNITS + u]);
    } else if (i < 20480) {
        const int j = i - 16384, u = j >> 6, k = j & 63;
        u2t[j] = (ushort)f2bfu(U2[k * UNITS + u]);
    }
}

// ---------------------------------------------------------------------------
// tableproj: table[v] = b1 + emb[v] @ W1 for all 10000 vocab rows.
// One wave per 16 vocab rows (625 waves). emb read f32 SEQUENTIALLY once;
// output row-major bf16 [v][64] so the scan gathers uint2 slices directly.
// ---------------------------------------------------------------------------
__global__ __launch_bounds__(256) void tableproj_kernel(
    const float* __restrict__ emb,
    const float* __restrict__ b1,
    const ushort* __restrict__ w1t,
    char* __restrict__ table)
{
    const int lane = threadIdx.x & 63;
    const int wid  = threadIdx.x >> 6;
    const int gw   = blockIdx.x * 4 + wid;
    if (gw >= NVWV) return;
    const int m15  = lane & 15;
    const int kgrp = lane >> 4;
    const int v    = gw * 16 + m15;
    const int vc   = v < NVOC ? v : NVOC - 1;      // 625*16 == 10000, exact; safe anyway

    bf16x8 aW1[4][4];
    #pragma unroll
    for (int mt = 0; mt < 4; ++mt)
        #pragma unroll
        for (int ks = 0; ks < 4; ++ks)
            aW1[mt][ks] = *(const bf16x8*)(w1t + (16 * mt + m15) * 128 + kgrp * 8 + 32 * ks);

    const float* rp = emb + (size_t)vc * EMBED;
    bf16x8 bf[4];
    #pragma unroll
    for (int ks = 0; ks < 3; ++ks) {
        f32x4 e0 = *(const f32x4*)(rp + kgrp * 8 + 32 * ks);
        f32x4 e1 = *(const f32x4*)(rp + kgrp * 8 + 32 * ks + 4);
        uint4 u;
        u.x = cvtpk(e0.x, e0.y); u.y = cvtpk(e0.z, e0.w);
        u.z = cvtpk(e1.x, e1.y); u.w = cvtpk(e1.z, e1.w);
        bf[ks] = *(bf16x8*)&u;
    }
    {   // ks=3: only e=96..99 valid (kgrp 0)
        uint4 u = {0u, 0u, 0u, 0u};
        if (kgrp == 0) {
            f32x4 e0 = *(const f32x4*)(rp + 96);
            u.x = cvtpk(e0.x, e0.y); u.y = cvtpk(e0.z, e0.w);
        }
        bf[3] = *(bf16x8*)&u;
    }

    f32x4 acc[4];
    #pragma unroll
    for (int mt = 0; mt < 4; ++mt)
        acc[mt] = *(const f32x4*)(b1 + 16 * mt + 4 * kgrp);
    #pragma unroll
    for (int ks = 0; ks < 4; ++ks)
        #pragma unroll
        for (int mt = 0; mt < 4; ++mt)
            acc[mt] = MFMA16(aW1[mt][ks], bf[ks], acc[mt], 0, 0, 0);

    // store: row v, units 16mt+4kgrp..+3 -> byte v*128 + mt*32 + kgrp*8
    #pragma unroll
    for (int mt = 0; mt < 4; ++mt) {
        uint2 q;
        q.x = cvtpk(acc[mt][0], acc[mt][1]);
        q.y = cvtpk(acc[mt][2], acc[mt][3]);
        *(uint2*)(table + (size_t)v * 128 + mt * 32 + kgrp * 8) = q;
    }
}

// ---------------------------------------------------------------------------
// rnn: R8 lean scan (verified ~30us) with the xw HBM stream replaced by an
// L2-resident table gather: per phase 1 token load + 1 uint2 gather,
// pipelined 3 phases deep. 4 waves/block M-split, 256 blocks.
// ---------------------------------------------------------------------------
__global__ __launch_bounds__(256, 1) void rnn_kernel(
    const int*    __restrict__ tokens,
    const uint2*  __restrict__ table,    // [10000][16] uint2
    const ushort* __restrict__ u1t,
    const ushort* __restrict__ w2t,
    const ushort* __restrict__ u2t,
    const float*  __restrict__ b2,
    const float*  __restrict__ Wo,
    const float*  __restrict__ bo,
    float*        __restrict__ out)
{
    __shared__ __align__(16) char h1L[2][2048];   // [buf][16b x 64u bf16, swz]
    __shared__ __align__(16) char h2L[2][2048];
    __shared__ float headp[4][16];

    const int lane = threadIdx.x & 63;
    const int w    = threadIdx.x >> 6;
    const int m15  = lane & 15;
    const int kgrp = lane >> 4;
    const int swz  = (m15 & 7) << 4;
    const int wg   = blockIdx.x;

    {
        uint4 z = {0u, 0u, 0u, 0u};
        if (threadIdx.x < 128) ((uint4*)h2L[0])[threadIdx.x] = z;
    }

    const int urow = 16 * w + m15;
    bf16x8 aU1[2], aW2[2], aU2[2];
    #pragma unroll
    for (int ks = 0; ks < 2; ++ks) {
        aU1[ks] = *(const bf16x8*)(u1t + urow * 64 + kgrp * 8 + 32 * ks);
        aW2[ks] = *(const bf16x8*)(w2t + urow * 64 + kgrp * 8 + 32 * ks);
        aU2[ks] = *(const bf16x8*)(u2t + urow * 64 + kgrp * 8 + 32 * ks);
    }
    const int ubase = 16 * w + 4 * kgrp;
    const f32x4 b2c = *(const f32x4*)(b2 + ubase);

    // token -> table-fragment pipeline (this wave's slice: +w*4+kgrp)
    const int*   tokp = tokens + (size_t)(wg * 16 + m15) * SEQ;
    const uint2* tabp = table + w * 4 + kgrp;

    const int tok0 = tokp[0];
    const int tok1 = tokp[1];
    const int tok2 = tokp[2];
    int tokC       = tokp[3];
    uint2 q0 = tabp[(size_t)tok0 * 16];
    uint2 qA = tabp[(size_t)tok1 * 16];
    uint2 qB = tabp[(size_t)tok2 * 16];

    // prologue: h1[0] = tanh(xw[0]) -> buf 0
    {
        float t0 = fast_tanh(bflo(q0.x)), t1 = fast_tanh(bfhi(q0.x));
        float t2 = fast_tanh(bflo(q0.y)), t3 = fast_tanh(bfhi(q0.y));
        uint2 pk; pk.x = cvtpk(t0, t1); pk.y = cvtpk(t2, t3);
        *(uint2*)(h1L[0] + m15 * 128 + ((32 * w + 8 * kgrp) ^ swz)) = pk;
    }
    asm volatile("s_waitcnt lgkmcnt(0)" ::: "memory");
    __builtin_amdgcn_s_barrier();

    float d2f0 = 0.f, d2f1 = 0.f, d2f2 = 0.f, d2f3 = 0.f;

#define LBAR() do { asm volatile("s_waitcnt lgkmcnt(0)" ::: "memory"); \
                    __builtin_amdgcn_s_barrier(); } while (0)
// Phase T: qA holds frag[T+1]; gather frag[T+3] via tokC; load token[T+4].
#define PHASE(T, P, Q)                                                           \
  {                                                                              \
    uint2 qC = tabp[(size_t)tokC * 16];                                          \
    const int tn = ((T) + 4 < SEQ) ? (T) + 4 : SEQ - 1;                          \
    tokC = tokp[tn];                                                             \
    bf16x8 bh1a = *(const bf16x8*)(h1L[P] + m15 * 128 + ((kgrp * 16     ) ^ swz)); \
    bf16x8 bh1b = *(const bf16x8*)(h1L[P] + m15 * 128 + ((kgrp * 16 + 64) ^ swz)); \
    bf16x8 bh2a = *(const bf16x8*)(h2L[P] + m15 * 128 + ((kgrp * 16     ) ^ swz)); \
    bf16x8 bh2b = *(const bf16x8*)(h2L[P] + m15 * 128 + ((kgrp * 16 + 64) ^ swz)); \
    f32x4 d1 = {bflo(qA.x), bfhi(qA.x), bflo(qA.y), bfhi(qA.y)};                 \
    d1 = MFMA16(aU1[0], bh1a, d1, 0, 0, 0);                                      \
    d1 = MFMA16(aU1[1], bh1b, d1, 0, 0, 0);                                      \
    f32x4 dC = b2c;                                                              \
    dC = MFMA16(aW2[0], bh1a, dC, 0, 0, 0);                                      \
    dC = MFMA16(aW2[1], bh1b, dC, 0, 0, 0);                                      \
    f32x4 dD = {0.f, 0.f, 0.f, 0.f};                                             \
    dD = MFMA16(aU2[0], bh2a, dD, 0, 0, 0);                                      \
    dD = MFMA16(aU2[1], bh2b, dD, 0, 0, 0);                                      \
    float n0 = fast_tanh(d1[0]);                                                 \
    float n1 = fast_tanh(d1[1]);                                                 \
    float n2 = fast_tanh(d1[2]);                                                 \
    float n3 = fast_tanh(d1[3]);                                                 \
    d2f0 = fast_tanh(dC[0] + dD[0]);                                             \
    d2f1 = fast_tanh(dC[1] + dD[1]);                                             \
    d2f2 = fast_tanh(dC[2] + dD[2]);                                             \
    d2f3 = fast_tanh(dC[3] + dD[3]);                                             \
    {                                                                            \
        uint2 pk; pk.x = cvtpk(n0, n1); pk.y = cvtpk(n2, n3);                    \
        *(uint2*)(h1L[Q] + m15 * 128 + ((32 * w + 8 * kgrp) ^ swz)) = pk;        \
    }                                                                            \
    {                                                                            \
        uint2 pk; pk.x = cvtpk(d2f0, d2f1); pk.y = cvtpk(d2f2, d2f3);            \
        *(uint2*)(h2L[Q] + m15 * 128 + ((32 * w + 8 * kgrp) ^ swz)) = pk;        \
    }                                                                            \
    LBAR();                                                                      \
    qA = qB; qB = qC;                                                            \
  }

    for (int t = 0; t < SEQ; t += 2) {
        PHASE(t,     0, 1)
        PHASE(t + 1, 1, 0)
    }
#undef PHASE
#undef LBAR

    // ---- head: out[b] = sigmoid(h2[79] @ Wo + bo) ----
    const f32x4 woc = *(const f32x4*)(Wo + ubase);
    float p = d2f0 * woc[0] + d2f1 * woc[1] + d2f2 * woc[2] + d2f3 * woc[3];
    p += __shfl_xor(p, 16, 64);
    p += __shfl_xor(p, 32, 64);
    if (lane < 16) headp[w][lane] = p;
    __syncthreads();
    if (threadIdx.x < 16) {
        const float z = headp[0][threadIdx.x] + headp[1][threadIdx.x]
                      + headp[2][threadIdx.x] + headp[3][threadIdx.x] + bo[0];
        const float e = __builtin_amdgcn_exp2f(-z * 1.4426950408889634f);
        out[wg * 16 + threadIdx.x] = __builtin_amdgcn_rcpf(1.0f + e);
    }
}

extern "C" void kernel_launch(void* const* d_in, const int* in_sizes, int n_in,
                              void* d_out, int out_size, void* d_ws, size_t ws_size,
                              hipStream_t stream) {
    const int*   tokens = (const int*)  d_in[0];
    const float* emb    = (const float*)d_in[1];
    const float* W1     = (const float*)d_in[2];
    const float* U1     = (const float*)d_in[3];
    const float* b1     = (const float*)d_in[4];
    const float* W2     = (const float*)d_in[5];
    const float* U2     = (const float*)d_in[6];
    const float* b2     = (const float*)d_in[7];
    const float* Wo     = (const float*)d_in[8];
    const float* bo     = (const float*)d_in[9];
    float* out = (float*)d_out;
    char*  ws  = (char*)d_ws;

    miniprep_kernel<<<80, 256, 0, stream>>>(W1, U1, W2, U2, ws);
    tableproj_kernel<<<(NVWV + 3) / 4, 256, 0, stream>>>(
        emb, b1, (const ushort*)(ws + W1T_OFF), ws + TAB_OFF);
    rnn_kernel<<<NTILE, 256, 0, stream>>>(
        tokens, (const uint2*)(ws + TAB_OFF),
        (const ushort*)(ws + U1T_OFF), (const ushort*)(ws + W2T_OFF),
        (const ushort*)(ws + U2T_OFF),
        b2, Wo, bo, out);
}

// Round 12
// 50.039 us; speedup vs baseline: 1.1894x; 1.1894x over previous
//
#include <hip/hip_runtime.h>

#define BATCH 4096
#define SEQ   80
#define EMBED 100
#define UNITS 64
#define NTILE (BATCH / 16)      // 256 batch tiles of 16 rows
#define NHALF (NTILE * 2)       // 512 half-tiles of 8 rows -> 2 blocks/CU
#define NVOC  10000
#define NVWV  ((NVOC + 15) / 16)   // 625 vocab tiles of 16 rows

typedef float f32x4  __attribute__((ext_vector_type(4)));
typedef short bf16x8 __attribute__((ext_vector_type(8)));

#define MFMA16 __builtin_amdgcn_mfma_f32_16x16x32_bf16

// ---- ws layout (bytes) ----
#define TAB_OFF 0u           // bf16 table[10000][64] = 1,280,000 B (L2-resident)
#define W1T_OFF 1280000u     // ushort[64*128] (k zero-padded to 128)
#define U1T_OFF 1296384u     // ushort[64*64]
#define W2T_OFF 1304576u
#define U2T_OFF 1312768u     // end = 1,320,960 B

__device__ __forceinline__ unsigned f2bfu(float f) {
    union { float f; unsigned u; } x; x.f = f;
    return (x.u + 0x7fffu + ((x.u >> 16) & 1u)) >> 16;   // RNE
}
__device__ __forceinline__ unsigned cvtpk(float lo, float hi) {
    unsigned r;
    asm("v_cvt_pk_bf16_f32 %0, %1, %2" : "=v"(r) : "v"(lo), "v"(hi));
    return r;
}
__device__ __forceinline__ float bflo(unsigned u) {
    union { unsigned u; float f; } x; x.u = u << 16; return x.f;
}
__device__ __forceinline__ float bfhi(unsigned u) {
    union { unsigned u; float f; } x; x.u = u & 0xffff0000u; return x.f;
}
// branch-free exact-tails tanh: 1 - 2/(e^{2x}+1)
__device__ __forceinline__ float fast_tanh(float x) {
    float e = __builtin_amdgcn_exp2f(x * 2.8853900817779268f);   // e^{2x}
    float r = __builtin_amdgcn_rcpf(e + 1.0f);
    return __builtin_fmaf(-2.0f, r, 1.0f);
}

// ---------------------------------------------------------------------------
// miniprep: transposed bf16 weight tables only (20480 elems total).
// ---------------------------------------------------------------------------
__global__ __launch_bounds__(256) void miniprep_kernel(
    const float* __restrict__ W1, const float* __restrict__ U1,
    const float* __restrict__ W2, const float* __restrict__ U2,
    char* __restrict__ ws)
{
    ushort* w1t = (ushort*)(ws + W1T_OFF);
    ushort* u1t = (ushort*)(ws + U1T_OFF);
    ushort* w2t = (ushort*)(ws + W2T_OFF);
    ushort* u2t = (ushort*)(ws + U2T_OFF);
    const int i = blockIdx.x * 256 + threadIdx.x;
    if (i < 8192) {                       // w1t[u][k], k padded to 128
        const int u = i >> 7, k = i & 127;
        w1t[i] = (k < EMBED) ? (ushort)f2bfu(W1[k * UNITS + u]) : (ushort)0;
    } else if (i < 12288) {
        const int j = i - 8192, u = j >> 6, k = j & 63;
        u1t[j] = (ushort)f2bfu(U1[k * UNITS + u]);
    } else if (i < 16384) {
        const int j = i - 12288, u = j >> 6, k = j & 63;
        w2t[j] = (ushort)f2bfu(W2[k * UNITS + u]);
    } else if (i < 20480) {
        const int j = i - 16384, u = j >> 6, k = j & 63;
        u2t[j] = (ushort)f2bfu(U2[k * UNITS + u]);
    }
}

// ---------------------------------------------------------------------------
// tableproj: table[v] = b1 + emb[v] @ W1 for all 10000 vocab rows. (verified)
// ---------------------------------------------------------------------------
__global__ __launch_bounds__(256) void tableproj_kernel(
    const float* __restrict__ emb,
    const float* __restrict__ b1,
    const ushort* __restrict__ w1t,
    char* __restrict__ table)
{
    const int lane = threadIdx.x & 63;
    const int wid  = threadIdx.x >> 6;
    const int gw   = blockIdx.x * 4 + wid;
    if (gw >= NVWV) return;
    const int m15  = lane & 15;
    const int kgrp = lane >> 4;
    const int v    = gw * 16 + m15;
    const int vc   = v < NVOC ? v : NVOC - 1;

    bf16x8 aW1[4][4];
    #pragma unroll
    for (int mt = 0; mt < 4; ++mt)
        #pragma unroll
        for (int ks = 0; ks < 4; ++ks)
            aW1[mt][ks] = *(const bf16x8*)(w1t + (16 * mt + m15) * 128 + kgrp * 8 + 32 * ks);

    const float* rp = emb + (size_t)vc * EMBED;
    bf16x8 bf[4];
    #pragma unroll
    for (int ks = 0; ks < 3; ++ks) {
        f32x4 e0 = *(const f32x4*)(rp + kgrp * 8 + 32 * ks);
        f32x4 e1 = *(const f32x4*)(rp + kgrp * 8 + 32 * ks + 4);
        uint4 u;
        u.x = cvtpk(e0.x, e0.y); u.y = cvtpk(e0.z, e0.w);
        u.z = cvtpk(e1.x, e1.y); u.w = cvtpk(e1.z, e1.w);
        bf[ks] = *(bf16x8*)&u;
    }
    {
        uint4 u = {0u, 0u, 0u, 0u};
        if (kgrp == 0) {
            f32x4 e0 = *(const f32x4*)(rp + 96);
            u.x = cvtpk(e0.x, e0.y); u.y = cvtpk(e0.z, e0.w);
        }
        bf[3] = *(bf16x8*)&u;
    }

    f32x4 acc[4];
    #pragma unroll
    for (int mt = 0; mt < 4; ++mt)
        acc[mt] = *(const f32x4*)(b1 + 16 * mt + 4 * kgrp);
    #pragma unroll
    for (int ks = 0; ks < 4; ++ks)
        #pragma unroll
        for (int mt = 0; mt < 4; ++mt)
            acc[mt] = MFMA16(aW1[mt][ks], bf[ks], acc[mt], 0, 0, 0);

    #pragma unroll
    for (int mt = 0; mt < 4; ++mt) {
        uint2 q;
        q.x = cvtpk(acc[mt][0], acc[mt][1]);
        q.y = cvtpk(acc[mt][2], acc[mt][3]);
        *(uint2*)(table + (size_t)v * 128 + mt * 32 + kgrp * 8) = q;
    }
}

// ---------------------------------------------------------------------------
// rnn: half-tile stagger. 512 blocks x 4 waves (8 batch rows each, MFMA rows
// 8-15 duplicate row 0-7 data, outputs discarded) -> 2 independent blocks/CU
// -> 2 waves/SIMD from DIFFERENT barrier groups; stalls interleave.
// Feed: tokens preloaded to LDS (pad-84, conflict-free); table gather with
// 3-phase register rotation.
// ---------------------------------------------------------------------------
__global__ __launch_bounds__(256, 2) void rnn_kernel(
    const int*    __restrict__ tokens,
    const uint2*  __restrict__ table,    // [10000][16] uint2
    const ushort* __restrict__ u1t,
    const ushort* __restrict__ w2t,
    const ushort* __restrict__ u2t,
    const float*  __restrict__ b2,
    const float*  __restrict__ Wo,
    const float*  __restrict__ bo,
    float*        __restrict__ out)
{
    __shared__ __align__(16) char h1L[2][2048];   // [buf][16b x 64u bf16, swz]
    __shared__ __align__(16) char h2L[2][2048];
    __shared__ int   tokL[8][84];                 // pad 84: conflict-free
    __shared__ float headp[4][16];

    const int lane = threadIdx.x & 63;
    const int w    = threadIdx.x >> 6;
    const int m15  = lane & 15;
    const int m8   = m15 & 7;
    const int kgrp = lane >> 4;
    const int swz  = (m15 & 7) << 4;
    const int hb   = blockIdx.x;                  // half-tile id
    const int row_base = (hb >> 1) * 16 + (hb & 1) * 8;

    // zero h2[-1] (buf 0)
    {
        uint4 z = {0u, 0u, 0u, 0u};
        if (threadIdx.x < 128) ((uint4*)h2L[0])[threadIdx.x] = z;
    }
    // preload this half-tile's tokens (8 rows x 80) into LDS
    for (int i = threadIdx.x; i < 8 * SEQ; i += 256) {
        const int r = i / SEQ;
        const int t = i - r * SEQ;
        tokL[r][t] = tokens[(size_t)(row_base + r) * SEQ + t];
    }

    const int urow = 16 * w + m15;
    bf16x8 aU1[2], aW2[2], aU2[2];
    #pragma unroll
    for (int ks = 0; ks < 2; ++ks) {
        aU1[ks] = *(const bf16x8*)(u1t + urow * 64 + kgrp * 8 + 32 * ks);
        aW2[ks] = *(const bf16x8*)(w2t + urow * 64 + kgrp * 8 + 32 * ks);
        aU2[ks] = *(const bf16x8*)(u2t + urow * 64 + kgrp * 8 + 32 * ks);
    }
    const int ubase = 16 * w + 4 * kgrp;
    const f32x4 b2c = *(const f32x4*)(b2 + ubase);

    // token -> table-fragment pipeline (slice: + w*4 + kgrp)
    const int*   tokp = tokens + (size_t)(row_base + m8) * SEQ;
    const uint2* tabp = table + w * 4 + kgrp;

    const int tok0 = tokp[0];
    const int tok1 = tokp[1];
    const int tok2 = tokp[2];
    const int tok3 = tokp[3];
    int tokC       = tokp[4];
    uint2 q0 = tabp[(size_t)tok0 * 16];
    uint2 qA = tabp[(size_t)tok1 * 16];
    uint2 qB = tabp[(size_t)tok2 * 16];
    uint2 qC = tabp[(size_t)tok3 * 16];

    // prologue: h1[0] = tanh(xw[0]) -> buf 0
    {
        float t0 = fast_tanh(bflo(q0.x)), t1 = fast_tanh(bfhi(q0.x));
        float t2 = fast_tanh(bflo(q0.y)), t3 = fast_tanh(bfhi(q0.y));
        uint2 pk; pk.x = cvtpk(t0, t1); pk.y = cvtpk(t2, t3);
        *(uint2*)(h1L[0] + m15 * 128 + ((32 * w + 8 * kgrp) ^ swz)) = pk;
    }
    asm volatile("s_waitcnt lgkmcnt(0)" ::: "memory");
    __builtin_amdgcn_s_barrier();

    float d2f0 = 0.f, d2f1 = 0.f, d2f2 = 0.f, d2f3 = 0.f;

#define LBAR() do { asm volatile("s_waitcnt lgkmcnt(0)" ::: "memory"); \
                    __builtin_amdgcn_s_barrier(); } while (0)
// Phase T: qA holds frag[T+1]. Gather frag[T+4] via tokC (register);
// ds_read token[T+5] from LDS for next phase (covered by LBAR's lgkmcnt).
#define PHASE(T, P, Q)                                                           \
  {                                                                              \
    uint2 qD = tabp[(size_t)tokC * 16];                                          \
    const int tn = ((T) + 5 < SEQ) ? (T) + 5 : SEQ - 1;                          \
    const int tokN = tokL[m8][tn];                                               \
    bf16x8 bh1a = *(const bf16x8*)(h1L[P] + m15 * 128 + ((kgrp * 16     ) ^ swz)); \
    bf16x8 bh1b = *(const bf16x8*)(h1L[P] + m15 * 128 + ((kgrp * 16 + 64) ^ swz)); \
    bf16x8 bh2a = *(const bf16x8*)(h2L[P] + m15 * 128 + ((kgrp * 16     ) ^ swz)); \
    bf16x8 bh2b = *(const bf16x8*)(h2L[P] + m15 * 128 + ((kgrp * 16 + 64) ^ swz)); \
    f32x4 d1 = {bflo(qA.x), bfhi(qA.x), bflo(qA.y), bfhi(qA.y)};                 \
    d1 = MFMA16(aU1[0], bh1a, d1, 0, 0, 0);                                      \
    d1 = MFMA16(aU1[1], bh1b, d1, 0, 0, 0);                                      \
    f32x4 dC = b2c;                                                              \
    dC = MFMA16(aW2[0], bh1a, dC, 0, 0, 0);                                      \
    dC = MFMA16(aW2[1], bh1b, dC, 0, 0, 0);                                      \
    f32x4 dD = {0.f, 0.f, 0.f, 0.f};                                             \
    dD = MFMA16(aU2[0], bh2a, dD, 0, 0, 0);                                      \
    dD = MFMA16(aU2[1], bh2b, dD, 0, 0, 0);                                      \
    float n0 = fast_tanh(d1[0]);                                                 \
    float n1 = fast_tanh(d1[1]);                                                 \
    float n2 = fast_tanh(d1[2]);                                                 \
    float n3 = fast_tanh(d1[3]);                                                 \
    d2f0 = fast_tanh(dC[0] + dD[0]);                                             \
    d2f1 = fast_tanh(dC[1] + dD[1]);                                             \
    d2f2 = fast_tanh(dC[2] + dD[2]);                                             \
    d2f3 = fast_tanh(dC[3] + dD[3]);                                             \
    {                                                                            \
        uint2 pk; pk.x = cvtpk(n0, n1); pk.y = cvtpk(n2, n3);                    \
        *(uint2*)(h1L[Q] + m15 * 128 + ((32 * w + 8 * kgrp) ^ swz)) = pk;        \
    }                                                                            \
    {                                                                            \
        uint2 pk; pk.x = cvtpk(d2f0, d2f1); pk.y = cvtpk(d2f2, d2f3);            \
        *(uint2*)(h2L[Q] + m15 * 128 + ((32 * w + 8 * kgrp) ^ swz)) = pk;        \
    }                                                                            \
    LBAR();                                                                      \
    qA = qB; qB = qC; qC = qD; tokC = tokN;                                      \
  }

    for (int t = 0; t < SEQ; t += 2) {
        PHASE(t,     0, 1)
        PHASE(t + 1, 1, 0)
    }
#undef PHASE
#undef LBAR

    // ---- head: out[b] = sigmoid(h2[79] @ Wo + bo); 8 valid rows ----
    const f32x4 woc = *(const f32x4*)(Wo + ubase);
    float p = d2f0 * woc[0] + d2f1 * woc[1] + d2f2 * woc[2] + d2f3 * woc[3];
    p += __shfl_xor(p, 16, 64);
    p += __shfl_xor(p, 32, 64);
    if (lane < 16) headp[w][lane] = p;
    __syncthreads();
    if (threadIdx.x < 8) {
        const float z = headp[0][threadIdx.x] + headp[1][threadIdx.x]
                      + headp[2][threadIdx.x] + headp[3][threadIdx.x] + bo[0];
        const float e = __builtin_amdgcn_exp2f(-z * 1.4426950408889634f);
        out[row_base + threadIdx.x] = __builtin_amdgcn_rcpf(1.0f + e);
    }
}

extern "C" void kernel_launch(void* const* d_in, const int* in_sizes, int n_in,
                              void* d_out, int out_size, void* d_ws, size_t ws_size,
                              hipStream_t stream) {
    const int*   tokens = (const int*)  d_in[0];
    const float* emb    = (const float*)d_in[1];
    const float* W1     = (const float*)d_in[2];
    const float* U1     = (const float*)d_in[3];
    const float* b1     = (const float*)d_in[4];
    const float* W2     = (const float*)d_in[5];
    const float* U2     = (const float*)d_in[6];
    const float* b2     = (const float*)d_in[7];
    const float* Wo     = (const float*)d_in[8];
    const float* bo     = (const float*)d_in[9];
    float* out = (float*)d_out;
    char*  ws  = (char*)d_ws;

    miniprep_kernel<<<80, 256, 0, stream>>>(W1, U1, W2, U2, ws);
    tableproj_kernel<<<(NVWV + 3) / 4, 256, 0, stream>>>(
        emb, b1, (const ushort*)(ws + W1T_OFF), ws + TAB_OFF);
    rnn_kernel<<<NHALF, 256, 0, stream>>>(
        tokens, (const uint2*)(ws + TAB_OFF),
        (const ushort*)(ws + U1T_OFF), (const ushort*)(ws + W2T_OFF),
        (const ushort*)(ws + U2T_OFF),
        b2, Wo, bo, out);
}